// Round 1
// baseline (3365.161 us; speedup 1.0000x reference)
//
#include <hip/hip_runtime.h>

#define S_LEN 512
#define BATCH 64
#define EDIM  128
#define HDIM  256
#define GDIM  1024   // 4*H
#define TDIM  64
#define NROW  32768  // S*B

typedef __attribute__((ext_vector_type(8))) short short8;
typedef __attribute__((ext_vector_type(4))) short short4v;
typedef __attribute__((ext_vector_type(4))) float f32x4;

__device__ __forceinline__ unsigned short f2bf(float f) {
  unsigned u = __float_as_uint(f);
  u += 0x7FFFu + ((u >> 16) & 1u);   // RNE
  return (unsigned short)(u >> 16);
}
__device__ __forceinline__ float bf2f(unsigned short h) {
  return __uint_as_float(((unsigned)h) << 16);
}
// sigmoid/tanh: graceful at +-inf (rcp(inf)=0), inputs are data-bounded (~|x|<5)
__device__ __forceinline__ float sigm(float x) {
  float e = __expf(-x);
  return __builtin_amdgcn_rcpf(1.f + e);
}
__device__ __forceinline__ float tanh_(float x) {
  float e = __expf(2.f * x);
  return 1.f - 2.f * __builtin_amdgcn_rcpf(e + 1.f);
}

// ---------------- Kernel 1: gather + input projection (both directions) ----
// xq_d[sb][col] = bf16( emb[tok[sb]] . W_ih_d[col] + b_ih_d[col] + b_hh_d[col] )
__global__ __launch_bounds__(512) void k_proj(
    const int* __restrict__ tok, const float* __restrict__ emb,
    const float* __restrict__ Wf, const float* __restrict__ bihf, const float* __restrict__ bhhf,
    const float* __restrict__ Wb, const float* __restrict__ bihb, const float* __restrict__ bhhb,
    unsigned short* __restrict__ xqf, unsigned short* __restrict__ xqb) {
  __shared__ short xt[256 * 136];           // 256 rows x 128 bf16, pad->136 (2-way banks)
  const int tid = threadIdx.x;
  const int rowbase = blockIdx.x * 256;
  const int dir = blockIdx.y;
  const float* W  = dir ? Wb   : Wf;
  const float* bi = dir ? bihb : bihf;
  const float* bh = dir ? bhhb : bhhf;
  unsigned short* xq = dir ? xqb : xqf;

  // stage gathered embedding rows as bf16
  for (int i = tid; i < 256 * 32; i += 512) {
    int row = i >> 5, c4 = (i & 31) << 2;
    int t = tok[rowbase + row];
    float4 v = *(const float4*)(emb + (size_t)t * EDIM + c4);
    short4v p;
    p.x = (short)f2bf(v.x); p.y = (short)f2bf(v.y);
    p.z = (short)f2bf(v.z); p.w = (short)f2bf(v.w);
    *(short4v*)&xt[row * 136 + c4] = p;
  }
  __syncthreads();

  const int w = tid >> 6, l = tid & 63, q = l >> 4, cl = l & 15;

  // A fragments: lane holds A[row=l&15][k=(l>>4)*8 + j], 2 row-tiles per wave
  short8 a[2][4];
#pragma unroll
  for (int rt = 0; rt < 2; ++rt)
#pragma unroll
    for (int kk = 0; kk < 4; ++kk)
      a[rt][kk] = *(const short8*)&xt[((2 * w + rt) * 16 + cl) * 136 + kk * 32 + q * 8];

  for (int ct = 0; ct < 64; ++ct) {
    const int colg = ct * 16 + cl;
    // B fragments: B[k][n] = W[n][k]; lane holds col n=l&15, k-block (l>>4)*8
    short8 bw[4];
#pragma unroll
    for (int kk = 0; kk < 4; ++kk) {
      const float* wp = W + (size_t)colg * EDIM + kk * 32 + q * 8;
      float4 w0 = *(const float4*)wp;
      float4 w1 = *(const float4*)(wp + 4);
      short8 t8;
      t8[0] = (short)f2bf(w0.x); t8[1] = (short)f2bf(w0.y);
      t8[2] = (short)f2bf(w0.z); t8[3] = (short)f2bf(w0.w);
      t8[4] = (short)f2bf(w1.x); t8[5] = (short)f2bf(w1.y);
      t8[6] = (short)f2bf(w1.z); t8[7] = (short)f2bf(w1.w);
      bw[kk] = t8;
    }
    float bias = bi[colg] + bh[colg];
#pragma unroll
    for (int rt = 0; rt < 2; ++rt) {
      f32x4 acc = {bias, bias, bias, bias};
#pragma unroll
      for (int kk = 0; kk < 4; ++kk)
        acc = __builtin_amdgcn_mfma_f32_16x16x32_bf16(a[rt][kk], bw[kk], acc, 0, 0, 0);
      const int rowg = rowbase + (2 * w + rt) * 16 + q * 4;
#pragma unroll
      for (int r = 0; r < 4; ++r)
        xq[(size_t)(rowg + r) * GDIM + colg] = f2bf(acc[r]);   // C: row=(l>>4)*4+r, col=l&15
    }
  }
}

// ---------------- Kernel 2: the two LSTM scans (persistent, W_hh in VGPRs) --
// grid = 8: dir = bx&1, batch-group (16 rows) = bx>>1. 16 waves; wave owns 16 h-cols.
__global__ __launch_bounds__(1024) void k_lstm(
    const float* __restrict__ Whf, const float* __restrict__ Whb,
    const unsigned short* __restrict__ xqf, const unsigned short* __restrict__ xqb,
    unsigned short* __restrict__ hq) {
  __shared__ short hbuf[2][16][264];        // double-buffered h tile, bf16, padded
  const int tid = threadIdx.x;
  const int dir = blockIdx.x & 1, bg = blockIdx.x >> 1;
  const int w = tid >> 6, l = tid & 63, q = l >> 4, cl = l & 15;
  const int hidx = w * 16 + cl;             // this lane's gate/h column
  const float* Wh = dir ? Whb : Whf;
  const unsigned short* xq = dir ? xqb : xqf;

  // W_hh B-fragments, stationary: wf[gate][kstep], lane: col=l&15(+16w+256g), k=(l>>4)*8+j
  short8 wf[4][8];
#pragma unroll
  for (int gt = 0; gt < 4; ++gt) {
    const int cg = gt * 256 + hidx;
#pragma unroll
    for (int kk = 0; kk < 8; ++kk) {
      const float* wp = Wh + (size_t)cg * HDIM + kk * 32 + q * 8;
      float4 w0 = *(const float4*)wp;
      float4 w1 = *(const float4*)(wp + 4);
      short8 t8;
      t8[0] = (short)f2bf(w0.x); t8[1] = (short)f2bf(w0.y);
      t8[2] = (short)f2bf(w0.z); t8[3] = (short)f2bf(w0.w);
      t8[4] = (short)f2bf(w1.x); t8[5] = (short)f2bf(w1.y);
      t8[6] = (short)f2bf(w1.z); t8[7] = (short)f2bf(w1.w);
      wf[gt][kk] = t8;
    }
  }
  for (int i = tid; i < 2 * 16 * 264; i += 1024) ((short*)hbuf)[i] = 0;

  float c[4] = {0.f, 0.f, 0.f, 0.f};
  const int brow = bg * 16 + q * 4;         // base batch row for this lane's acc rows
  // prologue xp load for step 0
  unsigned short xpc[4][4];
  const int s0 = dir ? (S_LEN - 1) : 0;
#pragma unroll
  for (int gt = 0; gt < 4; ++gt)
#pragma unroll
    for (int r = 0; r < 4; ++r)
      xpc[gt][r] = xq[(size_t)(s0 * BATCH + brow + r) * GDIM + gt * 256 + hidx];
  __syncthreads();

  int cur = 0;
  for (int t = 0; t < S_LEN; ++t) {
    const int t2 = (t + 1 < S_LEN) ? t + 1 : t;
    const int s  = dir ? (S_LEN - 1 - t)  : t;
    const int s2 = dir ? (S_LEN - 1 - t2) : t2;
    // prefetch next step's xp (hides HBM latency under MFMA+gates)
    unsigned short xpn[4][4];
#pragma unroll
    for (int gt = 0; gt < 4; ++gt)
#pragma unroll
      for (int r = 0; r < 4; ++r)
        xpn[gt][r] = xq[(size_t)(s2 * BATCH + brow + r) * GDIM + gt * 256 + hidx];
    // A fragments from h(t-1)
    short8 a[8];
#pragma unroll
    for (int kk = 0; kk < 8; ++kk)
      a[kk] = *(const short8*)&hbuf[cur][cl][kk * 32 + q * 8];
    // acc init = xp (bias already folded in by k_proj), then 32 MFMAs
    f32x4 acc[4];
#pragma unroll
    for (int gt = 0; gt < 4; ++gt) {
      f32x4 t4 = {bf2f(xpc[gt][0]), bf2f(xpc[gt][1]), bf2f(xpc[gt][2]), bf2f(xpc[gt][3])};
      acc[gt] = t4;
    }
#pragma unroll
    for (int kk = 0; kk < 8; ++kk)
#pragma unroll
      for (int gt = 0; gt < 4; ++gt)
        acc[gt] = __builtin_amdgcn_mfma_f32_16x16x32_bf16(a[kk], wf[gt][kk], acc[gt], 0, 0, 0);
    // gates + state update (rows = brow..brow+3, col = hidx)
#pragma unroll
    for (int r = 0; r < 4; ++r) {
      float gi = sigm(acc[0][r]);
      float gf = sigm(acc[1][r]);
      float gg = tanh_(acc[2][r]);
      float go = sigm(acc[3][r]);
      float cn = gf * c[r] + gi * gg;
      c[r] = cn;
      float h = go * tanh_(cn);
      unsigned short hb = f2bf(h);
      hbuf[cur ^ 1][q * 4 + r][hidx] = (short)hb;
      hq[(size_t)(s * BATCH + brow + r) * 512 + dir * 256 + hidx] = hb;
    }
#pragma unroll
    for (int gt = 0; gt < 4; ++gt)
#pragma unroll
      for (int r = 0; r < 4; ++r)
        xpc[gt][r] = xpn[gt][r];
    __syncthreads();
    cur ^= 1;
  }
}

// ---------------- Kernel 3: output projection ------------------------------
__global__ __launch_bounds__(256) void k_out(
    const unsigned short* __restrict__ hq, const float* __restrict__ Wo,
    const float* __restrict__ bo, float* __restrict__ out) {
  __shared__ short wlds[64 * 520];          // W_out as bf16, padded
  const int tid = threadIdx.x;
  for (int i = tid; i < 64 * 128; i += 256) {
    int row = i >> 7, c4 = (i & 127) << 2;
    float4 v = *(const float4*)(Wo + (size_t)row * 512 + c4);
    short4v p;
    p.x = (short)f2bf(v.x); p.y = (short)f2bf(v.y);
    p.z = (short)f2bf(v.z); p.w = (short)f2bf(v.w);
    *(short4v*)&wlds[row * 520 + c4] = p;
  }
  __syncthreads();

  const int w = tid >> 6, l = tid & 63, q = l >> 4, cl = l & 15;
  const int rtb = blockIdx.x * 64 + w * 16;

  short8 a[16];
#pragma unroll
  for (int kk = 0; kk < 16; ++kk)
    a[kk] = *(const short8*)&hq[(size_t)(rtb + cl) * 512 + kk * 32 + q * 8];

#pragma unroll
  for (int ct = 0; ct < 4; ++ct) {
    float bias = bo[ct * 16 + cl];
    f32x4 acc = {bias, bias, bias, bias};
#pragma unroll
    for (int kk = 0; kk < 16; ++kk) {
      short8 b = *(const short8*)&wlds[(ct * 16 + cl) * 520 + kk * 32 + q * 8];
      acc = __builtin_amdgcn_mfma_f32_16x16x32_bf16(a[kk], b, acc, 0, 0, 0);
    }
#pragma unroll
    for (int r = 0; r < 4; ++r)
      out[(size_t)(rtb + q * 4 + r) * TDIM + ct * 16 + cl] = acc[r];
  }
}

extern "C" void kernel_launch(void* const* d_in, const int* in_sizes, int n_in,
                              void* d_out, int out_size, void* d_ws, size_t ws_size,
                              hipStream_t stream) {
  const int*   tok  = (const int*)d_in[0];
  const float* emb  = (const float*)d_in[1];
  const float* Wihf = (const float*)d_in[2];
  const float* Whhf = (const float*)d_in[3];
  const float* bihf = (const float*)d_in[4];
  const float* bhhf = (const float*)d_in[5];
  const float* Wihb = (const float*)d_in[6];
  const float* Whhb = (const float*)d_in[7];
  const float* bihb = (const float*)d_in[8];
  const float* bhhb = (const float*)d_in[9];
  const float* Wo   = (const float*)d_in[10];
  const float* bo   = (const float*)d_in[11];
  float* out = (float*)d_out;

  char* ws = (char*)d_ws;
  unsigned short* xqf = (unsigned short*)ws;                                  // 64 MiB
  unsigned short* xqb = (unsigned short*)(ws + (size_t)NROW * GDIM * 2);      // 64 MiB
  unsigned short* hq  = (unsigned short*)(ws + (size_t)NROW * GDIM * 4);      // 32 MiB

  k_proj<<<dim3(128, 2), 512, 0, stream>>>(tok, emb, Wihf, bihf, bhhf,
                                           Wihb, bihb, bhhb, xqf, xqb);
  k_lstm<<<8, 1024, 0, stream>>>(Whhf, Whhb, xqf, xqb, hq);
  k_out<<<512, 256, 0, stream>>>(hq, Wo, bo, out);
}